// Round 1
// baseline (112.504 us; speedup 1.0000x reference)
//
#include <hip/hip_runtime.h>

// Deformable conv (K=3, stride=1, pad=1, dil=1), N=8, Cin=Cout=128, H=W=64.
// Pipeline: prep_weight (fp32->bf16, [kk][co][c]) ; prep_x (NCHW fp32 -> NHWC bf16)
//           deform_main (bilinear im2col into LDS + bf16 MFMA GEMM, fp32 out).
// ws usage: xt = 8 MB at ws+0, wt = 288 KB at ws+8388608. Fully rewritten each launch.

#define H  64
#define W  64
#define CIN 128
#define COUT 128
#define NB 8
#define KK 9

typedef short bf16x8 __attribute__((ext_vector_type(8)));
typedef float f32x4  __attribute__((ext_vector_type(4)));

__device__ __forceinline__ unsigned short f2bf(float f) {
    unsigned u = __builtin_bit_cast(unsigned, f);
    u += 0x7FFFu + ((u >> 16) & 1u);          // round-nearest-even
    return (unsigned short)(u >> 16);
}
__device__ __forceinline__ float lo_f(unsigned u) { return __builtin_bit_cast(float, u << 16); }
__device__ __forceinline__ float hi_f(unsigned u) { return __builtin_bit_cast(float, u & 0xFFFF0000u); }

// w[co][c][kk] fp32 -> wt[kk][co][c] bf16
__global__ void prep_weight(const float* __restrict__ w, unsigned short* __restrict__ wt) {
    int idx = blockIdx.x * 256 + threadIdx.x;
    if (idx >= KK * COUT * CIN) return;
    int kk = idx / (COUT * CIN);
    int r  = idx - kk * (COUT * CIN);
    int co = r >> 7;
    int c  = r & 127;
    wt[idx] = f2bf(w[(co * CIN + c) * KK + kk]);
}

// x[n][c][y][x] fp32 -> xt[n][y][x][c] bf16 (LDS-tiled transpose, one (n,y) row per block)
__global__ void prep_x(const float* __restrict__ x, unsigned short* __restrict__ xt) {
    __shared__ float tile[CIN][W + 1];
    int b = blockIdx.x;                 // n*64 + y
    int n = b >> 6, y = b & 63;
    int t = threadIdx.x;
    int l = t & 63, g = t >> 6;         // lane, wave
    const float* src = x + ((size_t)n * CIN * H + y) * W;
    #pragma unroll
    for (int i = 0; i < 32; ++i) {
        int c = g * 32 + i;
        tile[c][l] = src[(size_t)c * H * W + l];   // coalesced 256B row per wave
    }
    __syncthreads();
    int xp = t >> 2;                    // x position 0..63
    int cb = (t & 3) * 32;              // channel base
    unsigned short* dst = xt + (((size_t)(n * H + y) * W + xp) * CIN + cb);
    unsigned rr[16];
    #pragma unroll
    for (int i = 0; i < 16; ++i) {
        float v0 = tile[cb + 2 * i][xp];
        float v1 = tile[cb + 2 * i + 1][xp];
        rr[i] = (unsigned)f2bf(v0) | ((unsigned)f2bf(v1) << 16);
    }
    #pragma unroll
    for (int i = 0; i < 4; ++i)
        ((uint4*)dst)[i] = make_uint4(rr[4*i], rr[4*i+1], rr[4*i+2], rr[4*i+3]);
}

// One block per (n, ho). 512 threads = 8 waves.
// Wave w: positions (w>>1)*16..+15 (wo), couts (w&1)*64..+63 (4 n-tiles of 16).
__global__ __launch_bounds__(512, 4) void deform_main(
        const float* __restrict__ offs, const unsigned short* __restrict__ xt,
        const unsigned short* __restrict__ wt, float* __restrict__ out) {
    // +8 bf16 pad per row: 16B-aligned b128 reads, 2-way bank aliasing only (free)
    __shared__ __attribute__((aligned(16))) unsigned short samp[64][CIN + 8];
    __shared__ __attribute__((aligned(16))) unsigned short wts[COUT][CIN + 8];

    int b = blockIdx.x;
    int n = b >> 6, ho = b & 63;
    int t = threadIdx.x;
    int lane = t & 63, wv = t >> 6;
    int lm = lane & 15, lq = lane >> 4;
    int prow = ((wv >> 1) << 4) + lm;       // sampled-row (== wo) for A frag, m = lane&15
    int cobase = (wv & 1) << 6;

    f32x4 acc[4] = {{0,0,0,0},{0,0,0,0},{0,0,0,0},{0,0,0,0}};

    // sampling work split: thread -> (position p, 16-channel chunk cb)
    int p  = t >> 3;                        // wo 0..63
    int cb = (t & 7) << 4;                  // channel base
    const float* offbase = offs + (((size_t)n * 2 * KK) * H + ho) * W + p;

    for (int kk = 0; kk < KK; ++kk) {
        // ---- stage weight tile wt[kk] -> wts[co][c] (B^T layout) ----
        {
            int co = t >> 2;
            int ch = (t & 3) << 5;
            const uint4* src = (const uint4*)(wt + (((size_t)kk * COUT + co) << 7) + ch);
            uint4* dst = (uint4*)&wts[co][ch];
            #pragma unroll
            for (int i = 0; i < 4; ++i) dst[i] = src[i];
        }
        // ---- bilinear-sample 16 channels for position p into samp[p][cb..] ----
        {
            float dy = offbase[(size_t)(2 * kk) * H * W];
            float dx = offbase[(size_t)(2 * kk + 1) * H * W];
            float py = (float)(ho - 1 + kk / 3) + dy;
            float px = (float)(p  - 1 + kk % 3) + dx;
            float y0f = floorf(py), x0f = floorf(px);
            float wy1 = py - y0f, wx1 = px - x0f;
            float wy0 = 1.f - wy1, wx0 = 1.f - wx1;
            int y0 = (int)y0f, x0 = (int)x0f;
            int y1 = y0 + 1, x1 = x0 + 1;
            bool vy0 = (unsigned)y0 < (unsigned)H, vy1 = (unsigned)y1 < (unsigned)H;
            bool vx0 = (unsigned)x0 < (unsigned)W, vx1 = (unsigned)x1 < (unsigned)W;
            float w00 = (vy0 && vx0) ? wy0 * wx0 : 0.f;
            float w01 = (vy0 && vx1) ? wy0 * wx1 : 0.f;
            float w10 = (vy1 && vx0) ? wy1 * wx0 : 0.f;
            float w11 = (vy1 && vx1) ? wy1 * wx1 : 0.f;
            int yc0 = min(max(y0, 0), H - 1), yc1 = min(max(y1, 0), H - 1);
            int xc0 = min(max(x0, 0), W - 1), xc1 = min(max(x1, 0), W - 1);
            const unsigned short* r0 = xt + (size_t)(n * H + yc0) * W * CIN + cb;
            const unsigned short* r1 = xt + (size_t)(n * H + yc1) * W * CIN + cb;
            const unsigned short* b00 = r0 + xc0 * CIN;
            const unsigned short* b01 = r0 + xc1 * CIN;
            const unsigned short* b10 = r1 + xc0 * CIN;
            const unsigned short* b11 = r1 + xc1 * CIN;
            #pragma unroll
            for (int j = 0; j < 2; ++j) {
                uint4 q00 = *(const uint4*)(b00 + 8 * j);
                uint4 q01 = *(const uint4*)(b01 + 8 * j);
                uint4 q10 = *(const uint4*)(b10 + 8 * j);
                uint4 q11 = *(const uint4*)(b11 + 8 * j);
                const unsigned* a0 = (const unsigned*)&q00;
                const unsigned* a1 = (const unsigned*)&q01;
                const unsigned* a2 = (const unsigned*)&q10;
                const unsigned* a3 = (const unsigned*)&q11;
                unsigned rr[4];
                #pragma unroll
                for (int i = 0; i < 4; ++i) {
                    float v0 = w00*lo_f(a0[i]) + w01*lo_f(a1[i]) + w10*lo_f(a2[i]) + w11*lo_f(a3[i]);
                    float v1 = w00*hi_f(a0[i]) + w01*hi_f(a1[i]) + w10*hi_f(a2[i]) + w11*hi_f(a3[i]);
                    rr[i] = (unsigned)f2bf(v0) | ((unsigned)f2bf(v1) << 16);
                }
                *(uint4*)&samp[p][cb + 8 * j] = make_uint4(rr[0], rr[1], rr[2], rr[3]);
            }
        }
        __syncthreads();
        // ---- MFMA: A = samp (m=pos), B^T = wts (n=cout), K-chunk = 128 ch ----
        #pragma unroll
        for (int ct = 0; ct < 4; ++ct) {
            bf16x8 a = *(const bf16x8*)&samp[prow][(ct << 5) + (lq << 3)];
            #pragma unroll
            for (int nt = 0; nt < 4; ++nt) {
                bf16x8 bf = *(const bf16x8*)&wts[cobase + (nt << 4) + lm][(ct << 5) + (lq << 3)];
                acc[nt] = __builtin_amdgcn_mfma_f32_16x16x32_bf16(a, bf, acc[nt], 0, 0, 0);
            }
        }
        __syncthreads();   // protect LDS before next kk's staging
    }
    // epilogue: D[m=4*lq+r][n=lane&15] -> out[n][co][ho][wo], 4 consecutive wo = float4
    int wo = ((wv >> 1) << 4) + (lq << 2);
    #pragma unroll
    for (int nt = 0; nt < 4; ++nt) {
        int co = cobase + (nt << 4) + lm;
        *(f32x4*)(out + (((size_t)(n * COUT + co) * H + ho) * W + wo)) = acc[nt];
    }
}

extern "C" void kernel_launch(void* const* d_in, const int* in_sizes, int n_in,
                              void* d_out, int out_size, void* d_ws, size_t ws_size,
                              hipStream_t stream) {
    const float* x      = (const float*)d_in[0];   // (8,128,64,64)
    const float* offset = (const float*)d_in[1];   // (8,18,64,64)
    const float* weight = (const float*)d_in[2];   // (128,128,3,3)
    float* out = (float*)d_out;

    unsigned short* xt = (unsigned short*)d_ws;                                  // 8 MB
    unsigned short* wt = (unsigned short*)((char*)d_ws + (size_t)NB*H*W*CIN*2);  // 288 KB

    hipLaunchKernelGGL(prep_weight, dim3((KK*COUT*CIN + 255) / 256), dim3(256), 0, stream,
                       weight, wt);
    hipLaunchKernelGGL(prep_x, dim3(NB * H), dim3(256), 0, stream, x, xt);
    hipLaunchKernelGGL(deform_main, dim3(NB * H), dim3(512), 0, stream,
                       offset, xt, wt, out);
}